// Round 6
// baseline (83.253 us; speedup 1.0000x reference)
//
#include <hip/hip_runtime.h>
#include <math.h>

#define B_   4
#define L_   4096
#define C_   512
#define DM_  1024
#define HID_ 128
#define M_   (B_*L_)    // 16384
#define NC_  256        // chunks of 16 rows for scan2/scan3
#define CT_  16

typedef __attribute__((ext_vector_type(8))) short short8;
typedef __attribute__((ext_vector_type(4))) float f32x4;

__device__ __forceinline__ unsigned short f2bf(float f) {
  unsigned u = __float_as_uint(f);
  u += 0x7fffu + ((u >> 16) & 1u);
  return (unsigned short)(u >> 16);
}

// wrap(-theta) into (-pi, pi] == atan2(sin(-t), cos(-t))
__device__ __forceinline__ float wrap_neg(float th) {
  return 6.283185307179586f * rintf(th * 0.15915494309189535f) - th;
}

// ---- prep: transpose+cast weights to bf16 [n][k]
__global__ __launch_bounds__(256) void k_prep(const float* __restrict__ W1,
                                              const float* __restrict__ W2,
                                              unsigned short* __restrict__ W1T,
                                              unsigned short* __restrict__ W2T) {
  int idx = blockIdx.x * 256 + threadIdx.x;
  if (idx < DM_ * HID_) {
    int n = idx >> 10, k = idx & 1023;
    W1T[idx] = f2bf(W1[(size_t)k * HID_ + n]);
  }
  int i2 = idx - DM_ * HID_;
  if (i2 >= 0 && i2 < HID_ * C_) {
    int n = i2 >> 7, k = i2 & 127;
    W2T[i2] = f2bf(W2[(size_t)k * C_ + n]);
  }
}

// ---- mega: BM=32, 512 blocks (2/CU). Phase1 dbuf K-loop; H in LDS; phase2 dbuf
//      64-col chunks; epilogue writes Pi/K/R + 16-row affine composites (in-wave).
// LDS: A dbuf [0,8192), B1 dbuf [8192,40960), B2 dbuf [0,32768) (reuse), H [40960,49152)
__global__ __launch_bounds__(512) void k_mega(const float* __restrict__ X,
                                              const unsigned short* __restrict__ W1T,
                                              const float* __restrict__ b1,
                                              const unsigned short* __restrict__ W2T,
                                              const float* __restrict__ b2,
                                              const float* __restrict__ logPi,
                                              const float* __restrict__ theta,
                                              float* __restrict__ out1,
                                              float* __restrict__ out2,
                                              float* __restrict__ out3,
                                              float* __restrict__ Ab,
                                              float* __restrict__ Ub) {
  __shared__ char lds[49152];
  const int tid  = threadIdx.x;
  const int m0   = blockIdx.x * 32;
  const int lane = tid & 63;
  const int wave = tid >> 6;
  const int wr   = wave >> 2;      // 0..1 : 16-row half
  const int wc   = wave & 3;       // 0..3 : col group
  const int fr   = lane & 15;
  const int kg   = lane >> 4;      // 0..3

  // ---------------- phase 1: H = gelu(X @ W1 + b1), 32x128 ----------------
  f32x4 acc[2];
  acc[0] = (f32x4){0.f, 0.f, 0.f, 0.f};
  acc[1] = (f32x4){0.f, 0.f, 0.f, 0.f};

#define STAGE1(bufi, k0)                                                           \
  {                                                                                \
    if (tid < 256) {                                                               \
      int row = tid >> 3, k8 = tid & 7;                                            \
      const f32x4* src = (const f32x4*)(X + (size_t)(m0 + row) * DM_ + (k0) + k8 * 8); \
      f32x4 v0 = __builtin_nontemporal_load(src);                                  \
      f32x4 v1 = __builtin_nontemporal_load(src + 1);                              \
      uint4 pk;                                                                    \
      pk.x = f2bf(v0[0]) | ((unsigned)f2bf(v0[1]) << 16);                          \
      pk.y = f2bf(v0[2]) | ((unsigned)f2bf(v0[3]) << 16);                          \
      pk.z = f2bf(v1[0]) | ((unsigned)f2bf(v1[1]) << 16);                          \
      pk.w = f2bf(v1[2]) | ((unsigned)f2bf(v1[3]) << 16);                          \
      *(uint4*)(lds + (bufi) * 4096 + row * 128 + ((k8 ^ (row & 7)) << 4)) = pk;   \
    }                                                                              \
    _Pragma("unroll")                                                              \
    for (int t = 0; t < 2; ++t) {                                                  \
      int c = tid + t * 512;                                                       \
      int n = c >> 3, k8 = c & 7;                                                  \
      uint4 v = *(const uint4*)(W1T + (size_t)n * DM_ + (k0) + k8 * 8);            \
      *(uint4*)(lds + 8192 + (bufi) * 16384 + n * 128 + ((k8 ^ (n & 7)) << 4)) = v;\
    }                                                                              \
  }

  STAGE1(0, 0);
  __syncthreads();
  for (int it = 0; it < 16; ++it) {
    const int cur = it & 1;
    if (it < 15) STAGE1(1 - cur, (it + 1) * 64);
#pragma unroll
    for (int ks = 0; ks < 2; ++ks) {
      int row = wr * 16 + fr;
      short8 a = *(const short8*)(lds + cur * 4096 + row * 128 +
                                  (((ks * 4 + kg) ^ (row & 7)) << 4));
#pragma unroll
      for (int j = 0; j < 2; ++j) {
        int col = wc * 32 + j * 16 + fr;
        short8 b = *(const short8*)(lds + 8192 + cur * 16384 + col * 128 +
                                    (((ks * 4 + kg) ^ (col & 7)) << 4));
        acc[j] = __builtin_amdgcn_mfma_f32_16x16x32_bf16(a, b, acc[j], 0, 0, 0);
      }
    }
    __syncthreads();
  }
  // H epilogue -> LDS [40960,49152), bf16, swizzle-16 A-layout for phase 2
#pragma unroll
  for (int j = 0; j < 2; ++j) {
    int col = wc * 32 + j * 16 + fr;     // == phase-2 k index
    float bb = b1[col];
#pragma unroll
    for (int r = 0; r < 4; ++r) {
      int row = wr * 16 + kg * 4 + r;
      float x = acc[j][r] + bb;
      float g = 0.5f * x * (1.0f + erff(x * 0.70710678f));
      *(unsigned short*)(lds + 40960 + row * 256 +
                         (((col >> 3) ^ (row & 15)) << 4) + ((col & 7) << 1)) = f2bf(g);
    }
  }

  // ---------------- phase 2: 8 chunks of 64 cols, dbuf W2T ----------------
  const int bidx = m0 >> 12;
  const int ch   = ((m0 & 4095) >> 4) + wr;          // this wave's 16-row chunk
  const size_t chbase = ((size_t)(bidx * NC_ + ch)) * C_;

#define STAGE2(bufi, nc)                                                           \
  {                                                                                \
    _Pragma("unroll")                                                              \
    for (int t = 0; t < 2; ++t) {                                                  \
      int c = tid + t * 512;                                                       \
      int n = c >> 4, k8 = c & 15;                                                 \
      uint4 v = *(const uint4*)(W2T + (size_t)((nc) * 64 + n) * HID_ + k8 * 8);    \
      *(uint4*)(lds + (bufi) * 16384 + n * 256 + ((k8 ^ (n & 15)) << 4)) = v;      \
    }                                                                              \
  }

  STAGE2(0, 0);
  __syncthreads();
  for (int nc = 0; nc < 8; ++nc) {
    const int cur = nc & 1;
    if (nc < 7) STAGE2(1 - cur, nc + 1);

    f32x4 a2 = (f32x4){0.f, 0.f, 0.f, 0.f};
#pragma unroll
    for (int ks = 0; ks < 4; ++ks) {
      int row = wr * 16 + fr;
      short8 af = *(const short8*)(lds + 40960 + row * 256 +
                                   (((ks * 4 + kg) ^ (row & 15)) << 4));
      int col = wc * 16 + fr;
      short8 bf2 = *(const short8*)(lds + cur * 16384 + col * 256 +
                                    (((ks * 4 + kg) ^ (col & 15)) << 4));
      a2 = __builtin_amdgcn_mfma_f32_16x16x32_bf16(af, bf2, a2, 0, 0, 0);
    }

    // epilogue + in-register 16-row chunk composition
    {
      int col = nc * 64 + wc * 16 + fr;
      float Pi = expf(logPi[col]);
      float bb = b2[col];
      float A = 1.f, U = 0.f;
#pragma unroll
      for (int r = 0; r < 4; ++r) {
        int row = m0 + wr * 16 + kg * 4 + r;
        float lr = a2[r] + bb;
        lr = fminf(5.0f, fmaxf(-5.0f, lr));
        float R = expf(lr);
        float K = Pi / fmaxf(Pi + R, 1e-8f);
        size_t o = (size_t)row * C_ + col;
        __builtin_nontemporal_store(Pi, &out1[o]);
        out2[o] = K;
        __builtin_nontemporal_store(R, &out3[o]);
        float nu = wrap_neg(theta[o]);
        float a = 1.f - K;
        U = a * U + K * nu;
        A = a * A;
      }
      // ordered combine across kg lanes (butterfly)
      float oA = __shfl_xor(A, 16), oU = __shfl_xor(U, 16);
      if ((kg & 1) == 0) { U = oA * U + oU; A = oA * A; }
      else               { U = A * oU + U;  A = A * oA; }
      oA = __shfl_xor(A, 32); oU = __shfl_xor(U, 32);
      if ((kg & 2) == 0) { U = oA * U + oU; A = oA * A; }
      else               { U = A * oU + U;  A = A * oA; }
      if (kg == 0) { Ab[chbase + col] = A; Ub[chbase + col] = U; }
    }
    __syncthreads();
  }
}

// ---- scan2: block-level prefix over 256 chunks for 16 channels
__global__ __launch_bounds__(256) void k_scan2(const float* __restrict__ Ab,
                                               const float* __restrict__ Ub,
                                               float* __restrict__ D0) {
  __shared__ float cA[16][17], cU[16][17], carry[16][17];
  const int tid = threadIdx.x;
  const int b   = blockIdx.x >> 5;
  const int c0  = (blockIdx.x & 31) * 16;
  const int c_l = tid & 15, s = tid >> 4;   // 16 segs x 16 chunks
  const int c   = c0 + c_l;
  float A = 1.f, U = 0.f;
#pragma unroll
  for (int k = 0; k < 16; ++k) {
    size_t o = ((size_t)(b * NC_ + s * 16 + k)) * C_ + c;
    float a = Ab[o], u = Ub[o];
    U = a * U + u; A *= a;
  }
  cA[s][c_l] = A; cU[s][c_l] = U;
  __syncthreads();
  if (tid < 16) {
    float P = 0.f;
#pragma unroll
    for (int ss = 0; ss < 16; ++ss) {
      carry[ss][tid] = P;
      P = cA[ss][tid] * P + cU[ss][tid];
    }
  }
  __syncthreads();
  float d = carry[s][c_l];
#pragma unroll
  for (int k = 0; k < 16; ++k) {
    size_t o = ((size_t)(b * NC_ + s * 16 + k)) * C_ + c;
    D0[o] = d;
    d = Ab[o] * d + Ub[o];
  }
}

// ---- scan3: apply carry, out0 = theta + d
__global__ __launch_bounds__(256) void k_scan3(const float* __restrict__ Kv,
                                               const float* __restrict__ theta,
                                               const float* __restrict__ D0,
                                               float* __restrict__ out0) {
  const int b  = blockIdx.x / NC_;
  const int ch = blockIdx.x % NC_;
  const int c  = blockIdx.y * 256 + threadIdx.x;
  size_t base = ((size_t)b * L_ + (size_t)ch * CT_) * C_ + c;
  float d = D0[((size_t)(b * NC_ + ch)) * C_ + c];
#pragma unroll 4
  for (int j = 0; j < CT_; ++j) {
    size_t idx = base + (size_t)j * C_;
    float k  = Kv[idx];
    float th = theta[idx];
    float nu = wrap_neg(th);
    d = (1.f - k) * d + k * nu;
    __builtin_nontemporal_store(th + d, &out0[idx]);
  }
}

extern "C" void kernel_launch(void* const* d_in, const int* in_sizes, int n_in,
                              void* d_out, int out_size, void* d_ws, size_t ws_size,
                              hipStream_t stream) {
  const float* theta = (const float*)d_in[0];
  const float* X     = (const float*)d_in[1];
  const float* logPi = (const float*)d_in[2];
  const float* W1    = (const float*)d_in[3];
  const float* b1    = (const float*)d_in[4];
  const float* W2    = (const float*)d_in[5];
  const float* b2    = (const float*)d_in[6];

  float* out = (float*)d_out;
  const size_t S = (size_t)M_ * C_;
  float* out0 = out;
  float* out1 = out + S;
  float* out2 = out + 2 * S;
  float* out3 = out + 3 * S;

  unsigned short* W1T = (unsigned short*)d_ws;           // 131072 ush
  unsigned short* W2T = W1T + (size_t)DM_ * HID_;        // 65536 ush
  float* Ab = (float*)(W2T + (size_t)HID_ * C_);         // B*NC*C f32 each (2 MiB)
  float* Ub = Ab + (size_t)B_ * NC_ * C_;
  float* D0 = Ub + (size_t)B_ * NC_ * C_;

  hipLaunchKernelGGL(k_prep, dim3(768), dim3(256), 0, stream, W1, W2, W1T, W2T);
  hipLaunchKernelGGL(k_mega, dim3(M_ / 32), dim3(512), 0, stream,
                     X, W1T, b1, W2T, b2, logPi, theta, out1, out2, out3, Ab, Ub);
  hipLaunchKernelGGL(k_scan2, dim3(B_ * 32), dim3(256), 0, stream, Ab, Ub, D0);
  hipLaunchKernelGGL(k_scan3, dim3(B_ * NC_, 2), dim3(256), 0, stream, out2, theta, D0, out0);
}